// Round 17
// baseline (120.369 us; speedup 1.0000x reference)
//
#include <hip/hip_runtime.h>

// ---------------------------------------------------------------------------
// WelkirSelfAttention: B=4 S=1024 D=768 H=12 DH=64, relative_key_query bias +
// flow-type scalar bias. Pipeline (3 kernels):
//   k_prep : cast hidden/W{q,k,v} -> bf16; dist_emb -> bf16 * sqrt(c)
//   k_qkvf : MERGED GEMM + flow, INTERLEAVED ids (9 GEMM : 16 flow per 25)
//            so HBM-bound flow blocks co-reside with MFMA-bound GEMM blocks.
//            V blocks write V^T directly via LDS transpose.
//   k_attn : r15 kernel verbatim (77us proven).
// ---------------------------------------------------------------------------

typedef __attribute__((ext_vector_type(4))) float f32x4;
typedef __attribute__((ext_vector_type(8))) short s16x8;

#define MFMA_BF16 __builtin_amdgcn_mfma_f32_16x16x32_bf16
#define SQRT_C 0.42466086f  // sqrt(0.125 * log2(e))

__device__ __forceinline__ unsigned short f2bf(float x) {
  unsigned u = __builtin_bit_cast(unsigned, x);
  u += 0x7fffu + ((u >> 16) & 1u);
  return (unsigned short)(u >> 16);
}
__device__ __forceinline__ float bf2f(unsigned short h) {
  unsigned u = ((unsigned)h) << 16;
  return __builtin_bit_cast(float, u);
}
__device__ __forceinline__ float exp2_fast(float x) {
  float r;
  asm("v_exp_f32 %0, %1" : "=v"(r) : "v"(x));
  return r;
}
__device__ __forceinline__ void gl_lds16(const void* g, void* l) {
  __builtin_amdgcn_global_load_lds(
      (const __attribute__((address_space(1))) unsigned int*)g,
      (__attribute__((address_space(3))) unsigned int*)l, 16, 0, 0);
}

// ---------------------------------------------------------------------------
// k_prep: bf16 casts; dist rows pre-scaled by sqrt(c).
// ---------------------------------------------------------------------------
__global__ __launch_bounds__(256) void k_prep(
    const float* __restrict__ hs, const float* __restrict__ wq,
    const float* __restrict__ wk, const float* __restrict__ wv,
    const float* __restrict__ de, unsigned short* __restrict__ hsb,
    unsigned short* __restrict__ wb, unsigned short* __restrict__ db) {
  const long HSN = 3145728, WN = 1769472;
  long e = ((long)blockIdx.x * 256 + threadIdx.x) * 4;
  if (e < HSN) {
    float4 v = *(const float4*)(hs + e);
    *(ushort4*)(hsb + e) = make_ushort4(f2bf(v.x), f2bf(v.y), f2bf(v.z), f2bf(v.w));
  } else if (e < HSN + WN) {
    long ew = e - HSN;
    const float* src = (ew >= 1179648) ? wv : ((ew >= 589824) ? wk : wq);
    long off = (ew >= 1179648) ? (ew - 1179648) : ((ew >= 589824) ? (ew - 589824) : ew);
    float4 v = *(const float4*)(src + off);
    *(ushort4*)(wb + ew) = make_ushort4(f2bf(v.x), f2bf(v.y), f2bf(v.z), f2bf(v.w));
  } else {
    long ed = e - HSN - WN;  // [0, 131072)
    ushort4 ov;
    if (ed < 131008) {  // 2047*64 valid rows, rest zero pad
      float4 v = *(const float4*)(de + ed);
      ov = make_ushort4(f2bf(v.x * SQRT_C), f2bf(v.y * SQRT_C),
                        f2bf(v.z * SQRT_C), f2bf(v.w * SQRT_C));
    } else {
      ov = make_ushort4(0, 0, 0, 0);
    }
    *(ushort4*)(db + ed) = ov;
  }
}

// ---------------------------------------------------------------------------
// k_qkvf: merged GEMM + flow, dispatch-interleaved:
//   per 25 consecutive ids: ids%25<9 -> GEMM (576 total), else flow (1024).
//   GEMM: 128x128 tile BK=32; Q/K scatter *sqrt(c); V -> LDS transpose -> V^T.
//   flow: (ce+de+re)*log2e, idx0->0, attn per-lane tiled layout.
// ---------------------------------------------------------------------------
__global__ __launch_bounds__(256) void k_qkvf(
    const unsigned short* __restrict__ A, const unsigned short* __restrict__ W,
    const float* __restrict__ bq, const float* __restrict__ bk,
    const float* __restrict__ bv, unsigned short* __restrict__ Qp,
    unsigned short* __restrict__ Kp, unsigned short* __restrict__ Vt,
    const int* __restrict__ cm, const int* __restrict__ dm,
    const int* __restrict__ rm, const float* __restrict__ ce,
    const float* __restrict__ dfe, const float* __restrict__ rfe,
    unsigned short* __restrict__ flT) {
  __shared__ __align__(16) char smq[18432];
  const int tid = threadIdx.x;
  const int raw = blockIdx.x;
  const int grp = raw / 25, rem = raw % 25;

  if (rem >= 9) {
    // ---------------- flow path (no LDS, no barriers) ----------------
    const int fid = grp * 16 + (rem - 9);
    const int rt = fid & 15, lt = (fid >> 4) & 15, b = fid >> 8;
    const int l15 = tid & 15, g = (tid >> 4) & 3, w = tid >> 6;
    const int rowb = lt * 64 + w * 16 + g * 4;
    const int colb = rt * 64 + l15;
    s16x8 o0, o1;
#pragma unroll
    for (int n = 0; n < 4; ++n) {
#pragma unroll
      for (int r = 0; r < 4; ++r) {
        const long idx =
            ((long)b << 20) + ((long)(rowb + r) << 10) + colb + (n << 4);
        const int c = cm[idx], d = dm[idx], rr = rm[idx];
        const float v =
            (c ? ce[c] : 0.f) + (d ? dfe[d] : 0.f) + (rr ? rfe[rr] : 0.f);
        const short hv = (short)f2bf(1.4426950408889634f * v);
        if (n < 2) o0[n * 4 + r] = hv; else o1[(n - 2) * 4 + r] = hv;
      }
    }
    unsigned short* dst =
        flT + ((long)((((b << 4) + lt) << 4) | rt) << 12) + (tid << 4);
    *(s16x8*)(dst) = o0;
    *(s16x8*)(dst + 8) = o1;
    return;
  }

  // ---------------- GEMM path ----------------
  const int id = grp * 9 + rem;  // 0..575
  char* sa = smq;
  char* sb = smq + 8192;
  const int w = tid >> 6, lane = tid & 63;
  const int g = lane >> 4, l15 = lane & 15;
  const int bx = id % 18, by = id / 18;
  const int n0 = bx * 128, m0 = by * 128;
  const int wm = w >> 1, wn = w & 1;
  f32x4 acc[4][4] = {};
  for (int k0 = 0; k0 < 768; k0 += 32) {
#pragma unroll
    for (int it = 0; it < 2; ++it) {
      const int c = (w << 7) + (it << 6) + lane;
      const int row = c >> 2, sl = c & 3;
      const int so = ((sl ^ ((row >> 1) & 3)) << 3);
      char* dst = smq + ((w << 7) + (it << 6)) * 16;
      gl_lds16(A + (long)(m0 + row) * 768 + k0 + so, dst);
      gl_lds16(W + (long)(n0 + row) * 768 + k0 + so, dst + 8192);
    }
    __syncthreads();
    s16x8 af[4], bf[4];
#pragma unroll
    for (int mi = 0; mi < 4; ++mi) {
      const int row = wm * 64 + mi * 16 + l15;
      af[mi] = *(const s16x8*)(sa + row * 64 + ((g ^ ((row >> 1) & 3)) << 4));
    }
#pragma unroll
    for (int ni = 0; ni < 4; ++ni) {
      const int row = wn * 64 + ni * 16 + l15;
      bf[ni] = *(const s16x8*)(sb + row * 64 + ((g ^ ((row >> 1) & 3)) << 4));
    }
#pragma unroll
    for (int mi = 0; mi < 4; ++mi)
#pragma unroll
      for (int ni = 0; ni < 4; ++ni)
        acc[mi][ni] = MFMA_BF16(af[mi], bf[ni], acc[mi][ni], 0, 0, 0);
    __syncthreads();
  }
  const int t_sel = n0 / 768;
  if (t_sel < 2) {
    // ---- Q/K scatter epilogue, scaled by sqrt(c) ----
    const float* bias = (t_sel == 0) ? bq : bk;
    unsigned short* dst = (t_sel == 0) ? Qp : Kp;
#pragma unroll
    for (int ni = 0; ni < 4; ++ni) {
      const int mcol = n0 + wn * 64 + ni * 16 + l15;
      const int nw2 = mcol - t_sel * 768;
      const float bvv = bias[nw2];
      const int h = nw2 >> 6, dh = nw2 & 63;
#pragma unroll
      for (int mi = 0; mi < 4; ++mi) {
#pragma unroll
        for (int r = 0; r < 4; ++r) {
          const int token = m0 + wm * 64 + mi * 16 + (g << 2) + r;
          const int b = token >> 10, s = token & 1023;
          const long idx = ((((long)(b * 12 + h)) << 10) + s) * 64 + dh;
          dst[idx] = f2bf((acc[mi][ni][r] + bvv) * SQRT_C);
        }
      }
    }
  } else {
    // ---- V: LDS transpose -> V^T direct (two 64-dh halves) ----
    const int nv0 = n0 - 1536;               // 0,128,...,640
    const int b = m0 >> 10, s0 = m0 & 1023;  // 128 tokens all in batch b
    unsigned short* tv = (unsigned short*)smq;  // [128 rows][72 stride] u16
    const int dh = tid >> 2, seg = tid & 3;
#pragma unroll
    for (int hh = 0; hh < 2; ++hh) {
      if (wn == hh) {
#pragma unroll
        for (int ni = 0; ni < 4; ++ni) {
          const int colh = ni * 16 + l15;               // 0..63 within head
          const float bvv = bv[nv0 + hh * 64 + colh];
#pragma unroll
          for (int mi = 0; mi < 4; ++mi)
#pragma unroll
            for (int r = 0; r < 4; ++r)
              tv[(wm * 64 + mi * 16 + (g << 2) + r) * 72 + colh] =
                  f2bf(acc[mi][ni][r] + bvv);
        }
      }
      __syncthreads();
      const int hB = (nv0 >> 6) + hh;  // global head index
      unsigned short* vrow =
          Vt + ((long)((b * 12 + hB) * 64 + dh) << 10) + s0;
#pragma unroll
      for (int q = 0; q < 4; ++q) {
        s16x8 vv;
#pragma unroll
        for (int i = 0; i < 8; ++i)
          vv[i] = (short)tv[(seg * 32 + q * 8 + i) * 72 + dh];
        *(s16x8*)(vrow + seg * 32 + q * 8) = vv;
      }
      __syncthreads();
    }
  }
}

// ---------------------------------------------------------------------------
// k_attn: r15 verbatim. Per (b,h,l-tile of 64), 16 r-tiles.
// Static LDS 50688B (3 blocks/CU, tail-free: 768 = 3*256):
//   Kl/Vl/Dl swizzled gl_lds-staged; KDs stride-68 sheared; Pl stride-144.
// QD in registers + bpermute shear; KD b64 reads; max-free exp2 softmax.
// sqrt(c) pre-folded into Q, K, D sources -> s' = QK' + QD' + KD' + flow'.
// s_setprio(1) around MFMA clusters (3 independent blocks/CU = m191 regime).
// ---------------------------------------------------------------------------
__global__ __launch_bounds__(256, 3) void k_attn(
    const unsigned short* __restrict__ Qp, const unsigned short* __restrict__ Kp,
    const unsigned short* __restrict__ Vtp, const unsigned short* __restrict__ Db,
    const unsigned short* __restrict__ FlT, float* __restrict__ Out) {
  __shared__ __align__(16) char sm[50688];
  char* Kl = sm;
  char* Vl = sm + 8192;
  char* Dl = sm + 16384;
  unsigned short* KDs = (unsigned short*)(sm + 32768);  // [64] rows x stride 68
  char* Pl = sm + 41472;                                // [64] rows x 144B

  const int tid = threadIdx.x, w = tid >> 6, lane = tid & 63;
  const int g = lane >> 4, l15 = lane & 15;
  const int l0 = blockIdx.x << 6, h = blockIdx.y, b = blockIdx.z;
  const int bh = b * 12 + h;
  const unsigned short* Qb = Qp + ((long)bh << 16);
  const unsigned short* Kb = Kp + ((long)bh << 16);
  const unsigned short* Vb = Vtp + ((long)bh << 16);
  const unsigned short* fTb =
      FlT + ((long)(((b << 4) + blockIdx.x) << 4) << 12) + (tid << 4);

  const int qrow = l0 + (w << 4) + l15;
  const s16x8 qf0 = *(const s16x8*)(Qb + (long)qrow * 64 + g * 8);
  const s16x8 qf1 = *(const s16x8*)(Qb + (long)qrow * 64 + 32 + g * 8);

  // ---- iteration-invariant QD-shuffle constants ----
  int srcad[4];
  bool msk[4];
#pragma unroll
  for (int r = 0; r < 4; ++r) {
    const int bl = ((g << 2) + r - 1) & 15;
    srcad[r] = (((lane & 48) + ((bl - l15) & 15)) << 2);
    msk[r] = (l15 <= bl);
  }
  const bool g0 = (g == 0);

  f32x4 oacc[4] = {};
  float lpart[4] = {0.f, 0.f, 0.f, 0.f};

  for (int rt = 0; rt < 16; ++rt) {
    const int r0 = rt << 6;
    const int t0 = l0 - r0 + 960;  // window [t0, t0+127], t0 % 64 == 0

    // ---- flow tile: 2 x 16B vector loads (pre-tiled, pre-scaled) ----
    const s16x8 fv0 = *(const s16x8*)(fTb + ((long)rt << 12));
    const s16x8 fv1 = *(const s16x8*)(fTb + ((long)rt << 12) + 8);

    // ---- stage K / V^T (+ D half), pre-swizzled sources ----
#pragma unroll
    for (int it = 0; it < 2; ++it) {
      const int c = (w << 7) + (it << 6) + lane;
      const int row = c >> 3, sl = c & 7;
      const int so = ((sl ^ (row & 7)) << 3);
      char* dst = sm + ((w << 7) + (it << 6)) * 16;
      gl_lds16(Kb + (long)(r0 + row) * 64 + so, dst);            // K
      gl_lds16(Vb + (long)row * 1024 + r0 + so, dst + 8192);     // V^T
    }
    {
      const int nh = (rt == 0) ? 2 : 1;
      for (int hh = 0; hh < nh; ++hh) {
        const int ts = t0 + (hh << 6);
        char* dhalf = Dl + (((ts >> 6) & 1) << 13);
#pragma unroll
        for (int it = 0; it < 2; ++it) {
          const int c = (w << 7) + (it << 6) + lane;
          const int row = c >> 3, sl = c & 7;
          gl_lds16(Db + (long)(ts + row) * 64 + ((sl ^ (row & 7)) << 3),
                   dhalf + ((w << 7) + (it << 6)) * 16);
        }
      }
    }
    __syncthreads();

    // ---- QD panel: 5 tiles (n = w..w+4) kept in registers ----
    __builtin_amdgcn_s_setprio(1);
    f32x4 qa[5];
#pragma unroll
    for (int lt = 0; lt < 5; ++lt) {
      const int nq = w + lt;
      const int pb = ((((t0 >> 6) + (nq >> 2)) & 1) << 6) + ((nq & 3) << 4);
      const int trow = pb + l15;
      const s16x8 d0 = *(const s16x8*)(Dl + trow * 128 + ((g ^ (trow & 7)) << 4));
      const s16x8 d1 = *(const s16x8*)(Dl + trow * 128 + (((4 + g) ^ (trow & 7)) << 4));
      f32x4 a = {};
      a = MFMA_BF16(qf0, d0, a, 0, 0, 0);
      a = MFMA_BF16(qf1, d1, a, 0, 0, 0);
      qa[lt] = a;
    }

    // ---- KD panel: 5 tiles (n = 3-w..7-w) -> sheared LDS stores ----
    {
      const int krow = (w << 4) + l15;
      const s16x8 kf0 = *(const s16x8*)(Kl + krow * 128 + ((g ^ (krow & 7)) << 4));
      const s16x8 kf1 = *(const s16x8*)(Kl + krow * 128 + (((4 + g) ^ (krow & 7)) << 4));
#pragma unroll
      for (int kt = 0; kt < 5; ++kt) {
        const int nk = 3 - w + kt;
        const int pb = ((((t0 >> 6) + (nk >> 2)) & 1) << 6) + ((nk & 3) << 4);
        const int trow = pb + l15;
        const s16x8 d0 = *(const s16x8*)(Dl + trow * 128 + ((g ^ (trow & 7)) << 4));
        const s16x8 d1 = *(const s16x8*)(Dl + trow * 128 + (((4 + g) ^ (trow & 7)) << 4));
        f32x4 ka = {};
        ka = MFMA_BF16(kf0, d0, ka, 0, 0, 0);
        ka = MFMA_BF16(kf1, d1, ka, 0, 0, 0);
#pragma unroll
        for (int r = 0; r < 4; ++r) {
          const int prow = (w << 4) + (g << 2) + r;
          const int ck = (kt << 4) + l15 + (g << 2) + r - 15;  // w cancels
          if (kt == 0 || kt == 4) {
            if ((unsigned)ck < 64u) KDs[prow * 68 + ck] = f2bf(ka[r]);
          } else {
            KDs[prow * 68 + ck] = f2bf(ka[r]);
          }
        }
      }
    }
    __builtin_amdgcn_s_setprio(0);
    __syncthreads();

    // ---- scores: QK^T then QD-shuffle + KD(b64) + flow ----
    __builtin_amdgcn_s_setprio(1);
    f32x4 sacc[4] = {};
#pragma unroll
    for (int n = 0; n < 4; ++n) {
      const int kr = (n << 4) + l15;
      const s16x8 b0 = *(const s16x8*)(Kl + kr * 128 + ((g ^ (kr & 7)) << 4));
      const s16x8 b1 = *(const s16x8*)(Kl + kr * 128 + (((4 + g) ^ (kr & 7)) << 4));
      sacc[n] = MFMA_BF16(qf0, b0, sacc[n], 0, 0, 0);
      sacc[n] = MFMA_BF16(qf1, b1, sacc[n], 0, 0, 0);
    }
    __builtin_amdgcn_s_setprio(0);
#pragma unroll
    for (int n = 0; n < 4; ++n) {
      const int j = (n << 4) + l15;
      const uint2 kdp =
          *(const uint2*)(KDs + j * 68 + (w << 4) + (g << 2));  // 4x bf16
#pragma unroll
      for (int r = 0; r < 4; ++r) {
        float hi, lo;
        if (r == 0) {
          hi = g0 ? qa[3 - n][0] : qa[4 - n][0];
          lo = qa[3 - n][0];
        } else {
          hi = qa[4 - n][r];
          lo = qa[3 - n][r];
        }
        const float vsrc = msk[r] ? hi : lo;
        const float qd = __builtin_bit_cast(
            float, __builtin_amdgcn_ds_bpermute(
                       srcad[r], __builtin_bit_cast(int, vsrc)));
        const unsigned kdw = (r < 2) ? kdp.x : kdp.y;
        const float kd = bf2f((unsigned short)(kdw >> ((r & 1) << 4)));
        const float fv = bf2f((unsigned short)(
            n < 2 ? fv0[(n << 2) + r] : fv1[((n - 2) << 2) + r]));
        sacc[n][r] = sacc[n][r] + qd + kd + fv;  // all sqrt(c)-folded
      }
    }

    // ---- max-free softmax: P = exp2(s'), deferred per-lane row-sums ----
#pragma unroll
    for (int r = 0; r < 4; ++r) {
      const float p0 = exp2_fast(sacc[0][r]);
      const float p1 = exp2_fast(sacc[1][r]);
      const float p2 = exp2_fast(sacc[2][r]);
      const float p3 = exp2_fast(sacc[3][r]);
      sacc[0][r] = p0; sacc[1][r] = p1; sacc[2][r] = p2; sacc[3][r] = p3;
      lpart[r] += (p0 + p1) + (p2 + p3);
    }

    // ---- write P (wave-local rows; no barrier needed) ----
#pragma unroll
    for (int n = 0; n < 4; ++n) {
#pragma unroll
      for (int r = 0; r < 4; ++r) {
        const int ib = (w << 4) + (g << 2) + r;
        const int j = (n << 4) + l15;
        *(unsigned short*)(Pl + ib * 144 + (((j >> 3) ^ (ib & 7)) << 4) +
                           ((j & 7) << 1)) = f2bf(sacc[n][r]);
      }
    }

    // ---- PV ----
    __builtin_amdgcn_s_setprio(1);
#pragma unroll
    for (int k0 = 0; k0 < 2; ++k0) {
      const int prow = (w << 4) + l15;
      const s16x8 pf = *(const s16x8*)(
          Pl + prow * 144 + ((((k0 << 2) + g) ^ (prow & 7)) << 4));
#pragma unroll
      for (int n = 0; n < 4; ++n) {
        const int vrow = (n << 4) + l15;
        const s16x8 vf = *(const s16x8*)(
            Vl + vrow * 128 + ((((k0 << 2) + g) ^ (vrow & 7)) << 4));
        oacc[n] = MFMA_BF16(pf, vf, oacc[n], 0, 0, 0);
      }
    }
    __builtin_amdgcn_s_setprio(0);
    __syncthreads();
  }

  // ---- epilogue: single row-sum reduce, then out = oacc / lsum ----
  float lsum[4];
#pragma unroll
  for (int r = 0; r < 4; ++r) {
    float s = lpart[r];
#pragma unroll
    for (int dd = 1; dd < 16; dd <<= 1) s += __shfl_xor(s, dd, 64);
    lsum[r] = s;
  }
#pragma unroll
  for (int n = 0; n < 4; ++n) {
#pragma unroll
    for (int r = 0; r < 4; ++r) {
      const int l = l0 + (w << 4) + (g << 2) + r;
      const int d = (n << 4) + l15;
      Out[((long)(b * 1024 + l)) * 768 + h * 64 + d] = oacc[n][r] / lsum[r];
    }
  }
}

// ---------------------------------------------------------------------------
extern "C" void kernel_launch(void* const* d_in, const int* in_sizes, int n_in,
                              void* d_out, int out_size, void* d_ws, size_t ws_size,
                              hipStream_t stream) {
  const float* hs = (const float*)d_in[0];
  const float* Wq = (const float*)d_in[1];
  const float* bq = (const float*)d_in[2];
  const float* Wk = (const float*)d_in[3];
  const float* bk = (const float*)d_in[4];
  const float* Wv = (const float*)d_in[5];
  const float* bv = (const float*)d_in[6];
  const float* de = (const float*)d_in[7];
  const float* ce = (const float*)d_in[8];
  const float* dfe = (const float*)d_in[9];
  const float* rfe = (const float*)d_in[10];
  const int* cm = (const int*)d_in[11];
  const int* dm = (const int*)d_in[12];
  const int* rm = (const int*)d_in[13];
  float* out = (float*)d_out;
  char* ws = (char*)d_ws;

  unsigned short* hsb = (unsigned short*)(ws + 0);         // 6291456
  unsigned short* wb  = (unsigned short*)(ws + 6291456);   // 3538944
  unsigned short* db  = (unsigned short*)(ws + 9830400);   // 262144
  unsigned short* flT = (unsigned short*)(ws + 10092544);  // 8388608
  unsigned short* qp  = (unsigned short*)(ws + 18481152);  // 6291456
  unsigned short* kp  = (unsigned short*)(ws + 24772608);  // 6291456
  unsigned short* vt  = (unsigned short*)(ws + 37355520);  // 6291456

  k_prep<<<4928, 256, 0, stream>>>(hs, Wq, Wk, Wv, de, hsb, wb, db);
  k_qkvf<<<1600, 256, 0, stream>>>(hsb, wb, bq, bk, bv, qp, kp, vt,
                                   cm, dm, rm, ce, dfe, rfe, flT);
  k_attn<<<dim3(16, 12, 4), 256, 0, stream>>>(qp, kp, vt, db, flT, out);
}

// Round 18
// 112.510 us; speedup vs baseline: 1.0699x; 1.0699x over previous
//
#include <hip/hip_runtime.h>

// ---------------------------------------------------------------------------
// WelkirSelfAttention: B=4 S=1024 D=768 H=12 DH=64, relative_key_query bias +
// flow-type scalar bias. Pipeline (3 kernels):
//   k_prep : cast hidden/W{q,k,v} -> bf16; dist_emb -> bf16 * sqrt(c)
//   k_qkvf : MERGED GEMM + flow, r16 ordering (GEMM ids first — interleave
//            regressed 9us in r17: L2 adjacency + HBM contention).
//   k_attn : r15 + shared D-fragment loads between QD/KD panels (40 -> 28
//            pair-loads per block-iter).
// ---------------------------------------------------------------------------

typedef __attribute__((ext_vector_type(4))) float f32x4;
typedef __attribute__((ext_vector_type(8))) short s16x8;

#define MFMA_BF16 __builtin_amdgcn_mfma_f32_16x16x32_bf16
#define SQRT_C 0.42466086f  // sqrt(0.125 * log2(e))

__device__ __forceinline__ unsigned short f2bf(float x) {
  unsigned u = __builtin_bit_cast(unsigned, x);
  u += 0x7fffu + ((u >> 16) & 1u);
  return (unsigned short)(u >> 16);
}
__device__ __forceinline__ float bf2f(unsigned short h) {
  unsigned u = ((unsigned)h) << 16;
  return __builtin_bit_cast(float, u);
}
__device__ __forceinline__ float exp2_fast(float x) {
  float r;
  asm("v_exp_f32 %0, %1" : "=v"(r) : "v"(x));
  return r;
}
__device__ __forceinline__ void gl_lds16(const void* g, void* l) {
  __builtin_amdgcn_global_load_lds(
      (const __attribute__((address_space(1))) unsigned int*)g,
      (__attribute__((address_space(3))) unsigned int*)l, 16, 0, 0);
}

// ---------------------------------------------------------------------------
// k_prep: bf16 casts; dist rows pre-scaled by sqrt(c).
// ---------------------------------------------------------------------------
__global__ __launch_bounds__(256) void k_prep(
    const float* __restrict__ hs, const float* __restrict__ wq,
    const float* __restrict__ wk, const float* __restrict__ wv,
    const float* __restrict__ de, unsigned short* __restrict__ hsb,
    unsigned short* __restrict__ wb, unsigned short* __restrict__ db) {
  const long HSN = 3145728, WN = 1769472;
  long e = ((long)blockIdx.x * 256 + threadIdx.x) * 4;
  if (e < HSN) {
    float4 v = *(const float4*)(hs + e);
    *(ushort4*)(hsb + e) = make_ushort4(f2bf(v.x), f2bf(v.y), f2bf(v.z), f2bf(v.w));
  } else if (e < HSN + WN) {
    long ew = e - HSN;
    const float* src = (ew >= 1179648) ? wv : ((ew >= 589824) ? wk : wq);
    long off = (ew >= 1179648) ? (ew - 1179648) : ((ew >= 589824) ? (ew - 589824) : ew);
    float4 v = *(const float4*)(src + off);
    *(ushort4*)(wb + ew) = make_ushort4(f2bf(v.x), f2bf(v.y), f2bf(v.z), f2bf(v.w));
  } else {
    long ed = e - HSN - WN;  // [0, 131072)
    ushort4 ov;
    if (ed < 131008) {  // 2047*64 valid rows, rest zero pad
      float4 v = *(const float4*)(de + ed);
      ov = make_ushort4(f2bf(v.x * SQRT_C), f2bf(v.y * SQRT_C),
                        f2bf(v.z * SQRT_C), f2bf(v.w * SQRT_C));
    } else {
      ov = make_ushort4(0, 0, 0, 0);
    }
    *(ushort4*)(db + ed) = ov;
  }
}

// ---------------------------------------------------------------------------
// k_qkvf: merged GEMM + flow (r16 ordering: GEMM ids 0..575, flow 576+).
//   GEMM: 128x128 tile BK=32; Q/K scatter *sqrt(c); V -> LDS transpose -> V^T.
//   flow: (ce+de+re)*log2e, idx0->0, attn per-lane tiled layout.
// ---------------------------------------------------------------------------
__global__ __launch_bounds__(256) void k_qkvf(
    const unsigned short* __restrict__ A, const unsigned short* __restrict__ W,
    const float* __restrict__ bq, const float* __restrict__ bk,
    const float* __restrict__ bv, unsigned short* __restrict__ Qp,
    unsigned short* __restrict__ Kp, unsigned short* __restrict__ Vt,
    const int* __restrict__ cm, const int* __restrict__ dm,
    const int* __restrict__ rm, const float* __restrict__ ce,
    const float* __restrict__ dfe, const float* __restrict__ rfe,
    unsigned short* __restrict__ flT) {
  __shared__ __align__(16) char smq[18432];
  const int tid = threadIdx.x;
  const int id = blockIdx.x;

  if (id >= 576) {
    // ---------------- flow path (no LDS, no barriers) ----------------
    const int fid = id - 576;
    const int rt = fid & 15, lt = (fid >> 4) & 15, b = fid >> 8;
    const int l15 = tid & 15, g = (tid >> 4) & 3, w = tid >> 6;
    const int rowb = lt * 64 + w * 16 + g * 4;
    const int colb = rt * 64 + l15;
    s16x8 o0, o1;
#pragma unroll
    for (int n = 0; n < 4; ++n) {
#pragma unroll
      for (int r = 0; r < 4; ++r) {
        const long idx =
            ((long)b << 20) + ((long)(rowb + r) << 10) + colb + (n << 4);
        const int c = cm[idx], d = dm[idx], rr = rm[idx];
        const float v =
            (c ? ce[c] : 0.f) + (d ? dfe[d] : 0.f) + (rr ? rfe[rr] : 0.f);
        const short hv = (short)f2bf(1.4426950408889634f * v);
        if (n < 2) o0[n * 4 + r] = hv; else o1[(n - 2) * 4 + r] = hv;
      }
    }
    unsigned short* dst =
        flT + ((long)((((b << 4) + lt) << 4) | rt) << 12) + (tid << 4);
    *(s16x8*)(dst) = o0;
    *(s16x8*)(dst + 8) = o1;
    return;
  }

  // ---------------- GEMM path ----------------
  char* sa = smq;
  char* sb = smq + 8192;
  const int w = tid >> 6, lane = tid & 63;
  const int g = lane >> 4, l15 = lane & 15;
  const int bx = id % 18, by = id / 18;
  const int n0 = bx * 128, m0 = by * 128;
  const int wm = w >> 1, wn = w & 1;
  f32x4 acc[4][4] = {};
  for (int k0 = 0; k0 < 768; k0 += 32) {
#pragma unroll
    for (int it = 0; it < 2; ++it) {
      const int c = (w << 7) + (it << 6) + lane;
      const int row = c >> 2, sl = c & 3;
      const int so = ((sl ^ ((row >> 1) & 3)) << 3);
      char* dst = smq + ((w << 7) + (it << 6)) * 16;
      gl_lds16(A + (long)(m0 + row) * 768 + k0 + so, dst);
      gl_lds16(W + (long)(n0 + row) * 768 + k0 + so, dst + 8192);
    }
    __syncthreads();
    s16x8 af[4], bf[4];
#pragma unroll
    for (int mi = 0; mi < 4; ++mi) {
      const int row = wm * 64 + mi * 16 + l15;
      af[mi] = *(const s16x8*)(sa + row * 64 + ((g ^ ((row >> 1) & 3)) << 4));
    }
#pragma unroll
    for (int ni = 0; ni < 4; ++ni) {
      const int row = wn * 64 + ni * 16 + l15;
      bf[ni] = *(const s16x8*)(sb + row * 64 + ((g ^ ((row >> 1) & 3)) << 4));
    }
#pragma unroll
    for (int mi = 0; mi < 4; ++mi)
#pragma unroll
      for (int ni = 0; ni < 4; ++ni)
        acc[mi][ni] = MFMA_BF16(af[mi], bf[ni], acc[mi][ni], 0, 0, 0);
    __syncthreads();
  }
  const int t_sel = n0 / 768;
  if (t_sel < 2) {
    // ---- Q/K scatter epilogue, scaled by sqrt(c) ----
    const float* bias = (t_sel == 0) ? bq : bk;
    unsigned short* dst = (t_sel == 0) ? Qp : Kp;
#pragma unroll
    for (int ni = 0; ni < 4; ++ni) {
      const int mcol = n0 + wn * 64 + ni * 16 + l15;
      const int nw2 = mcol - t_sel * 768;
      const float bvv = bias[nw2];
      const int h = nw2 >> 6, dh = nw2 & 63;
#pragma unroll
      for (int mi = 0; mi < 4; ++mi) {
#pragma unroll
        for (int r = 0; r < 4; ++r) {
          const int token = m0 + wm * 64 + mi * 16 + (g << 2) + r;
          const int b = token >> 10, s = token & 1023;
          const long idx = ((((long)(b * 12 + h)) << 10) + s) * 64 + dh;
          dst[idx] = f2bf((acc[mi][ni][r] + bvv) * SQRT_C);
        }
      }
    }
  } else {
    // ---- V: LDS transpose -> V^T direct (two 64-dh halves) ----
    const int nv0 = n0 - 1536;               // 0,128,...,640
    const int b = m0 >> 10, s0 = m0 & 1023;  // 128 tokens all in batch b
    unsigned short* tv = (unsigned short*)smq;  // [128 rows][72 stride] u16
    const int dh = tid >> 2, seg = tid & 3;
#pragma unroll
    for (int hh = 0; hh < 2; ++hh) {
      if (wn == hh) {
#pragma unroll
        for (int ni = 0; ni < 4; ++ni) {
          const int colh = ni * 16 + l15;               // 0..63 within head
          const float bvv = bv[nv0 + hh * 64 + colh];
#pragma unroll
          for (int mi = 0; mi < 4; ++mi)
#pragma unroll
            for (int r = 0; r < 4; ++r)
              tv[(wm * 64 + mi * 16 + (g << 2) + r) * 72 + colh] =
                  f2bf(acc[mi][ni][r] + bvv);
        }
      }
      __syncthreads();
      const int hB = (nv0 >> 6) + hh;  // global head index
      unsigned short* vrow =
          Vt + ((long)((b * 12 + hB) * 64 + dh) << 10) + s0;
#pragma unroll
      for (int q = 0; q < 4; ++q) {
        s16x8 vv;
#pragma unroll
        for (int i = 0; i < 8; ++i)
          vv[i] = (short)tv[(seg * 32 + q * 8 + i) * 72 + dh];
        *(s16x8*)(vrow + seg * 32 + q * 8) = vv;
      }
      __syncthreads();
    }
  }
}

// ---------------------------------------------------------------------------
// k_attn: r15 + shared QD/KD D-fragment loads. Per (b,h,l-tile of 64).
// Static LDS 50688B (3 blocks/CU, tail-free: 768 = 3*256):
//   Kl/Vl/Dl swizzled gl_lds-staged; KDs stride-68 sheared; Pl stride-144.
// Panel: QD tile nq=w+lt and KD tile kt share the same D rows when
//   kt = lt + 2w-3; the merged loop computes both from one d0/d1 load
//   (28 pair-loads per block-iter vs 40). qa[lt] stays statically indexed.
// QD in registers + bpermute shear; KD b64 reads; max-free exp2 softmax.
// sqrt(c) pre-folded into Q, K, D -> s' = QK' + QD' + KD' + flow'.
// ---------------------------------------------------------------------------
__global__ __launch_bounds__(256, 3) void k_attn(
    const unsigned short* __restrict__ Qp, const unsigned short* __restrict__ Kp,
    const unsigned short* __restrict__ Vtp, const unsigned short* __restrict__ Db,
    const unsigned short* __restrict__ FlT, float* __restrict__ Out) {
  __shared__ __align__(16) char sm[50688];
  char* Kl = sm;
  char* Vl = sm + 8192;
  char* Dl = sm + 16384;
  unsigned short* KDs = (unsigned short*)(sm + 32768);  // [64] rows x stride 68
  char* Pl = sm + 41472;                                // [64] rows x 144B

  const int tid = threadIdx.x, w = tid >> 6, lane = tid & 63;
  const int g = lane >> 4, l15 = lane & 15;
  const int l0 = blockIdx.x << 6, h = blockIdx.y, b = blockIdx.z;
  const int bh = b * 12 + h;
  const unsigned short* Qb = Qp + ((long)bh << 16);
  const unsigned short* Kb = Kp + ((long)bh << 16);
  const unsigned short* Vb = Vtp + ((long)bh << 16);
  const unsigned short* fTb =
      FlT + ((long)(((b << 4) + blockIdx.x) << 4) << 12) + (tid << 4);

  const int qrow = l0 + (w << 4) + l15;
  const s16x8 qf0 = *(const s16x8*)(Qb + (long)qrow * 64 + g * 8);
  const s16x8 qf1 = *(const s16x8*)(Qb + (long)qrow * 64 + 32 + g * 8);

  // ---- iteration-invariant QD-shuffle constants ----
  int srcad[4];
  bool msk[4];
#pragma unroll
  for (int r = 0; r < 4; ++r) {
    const int bl = ((g << 2) + r - 1) & 15;
    srcad[r] = (((lane & 48) + ((bl - l15) & 15)) << 2);
    msk[r] = (l15 <= bl);
  }
  const bool g0 = (g == 0);
  const int kbase = (w << 1) - 3;  // kt = lt + kbase shares D with QD tile lt

  f32x4 oacc[4] = {};
  float lpart[4] = {0.f, 0.f, 0.f, 0.f};

  for (int rt = 0; rt < 16; ++rt) {
    const int r0 = rt << 6;
    const int t0 = l0 - r0 + 960;  // window [t0, t0+127], t0 % 64 == 0

    // ---- flow tile: 2 x 16B vector loads (pre-tiled, pre-scaled) ----
    const s16x8 fv0 = *(const s16x8*)(fTb + ((long)rt << 12));
    const s16x8 fv1 = *(const s16x8*)(fTb + ((long)rt << 12) + 8);

    // ---- stage K / V^T (+ D half), pre-swizzled sources ----
#pragma unroll
    for (int it = 0; it < 2; ++it) {
      const int c = (w << 7) + (it << 6) + lane;
      const int row = c >> 3, sl = c & 7;
      const int so = ((sl ^ (row & 7)) << 3);
      char* dst = sm + ((w << 7) + (it << 6)) * 16;
      gl_lds16(Kb + (long)(r0 + row) * 64 + so, dst);            // K
      gl_lds16(Vb + (long)row * 1024 + r0 + so, dst + 8192);     // V^T
    }
    {
      const int nh = (rt == 0) ? 2 : 1;
      for (int hh = 0; hh < nh; ++hh) {
        const int ts = t0 + (hh << 6);
        char* dhalf = Dl + (((ts >> 6) & 1) << 13);
#pragma unroll
        for (int it = 0; it < 2; ++it) {
          const int c = (w << 7) + (it << 6) + lane;
          const int row = c >> 3, sl = c & 7;
          gl_lds16(Db + (long)(ts + row) * 64 + ((sl ^ (row & 7)) << 3),
                   dhalf + ((w << 7) + (it << 6)) * 16);
        }
      }
    }
    __syncthreads();

    // ---- panels: merged QD + covered-KD, then leftover KD ----
    __builtin_amdgcn_s_setprio(1);
    const int krow = (w << 4) + l15;
    const s16x8 kf0 = *(const s16x8*)(Kl + krow * 128 + ((g ^ (krow & 7)) << 4));
    const s16x8 kf1 = *(const s16x8*)(Kl + krow * 128 + (((4 + g) ^ (krow & 7)) << 4));
    f32x4 qa[5];
#pragma unroll
    for (int lt = 0; lt < 5; ++lt) {
      const int nq = w + lt;
      const int pb = ((((t0 >> 6) + (nq >> 2)) & 1) << 6) + ((nq & 3) << 4);
      const int trow = pb + l15;
      const s16x8 d0 = *(const s16x8*)(Dl + trow * 128 + ((g ^ (trow & 7)) << 4));
      const s16x8 d1 = *(const s16x8*)(Dl + trow * 128 + (((4 + g) ^ (trow & 7)) << 4));
      f32x4 a = {};
      a = MFMA_BF16(qf0, d0, a, 0, 0, 0);
      a = MFMA_BF16(qf1, d1, a, 0, 0, 0);
      qa[lt] = a;
      const int kt = lt + kbase;  // runtime, wave-uniform
      if ((unsigned)kt < 5u) {    // this D tile also feeds KD tile kt
        f32x4 ka = {};
        ka = MFMA_BF16(kf0, d0, ka, 0, 0, 0);
        ka = MFMA_BF16(kf1, d1, ka, 0, 0, 0);
#pragma unroll
        for (int r = 0; r < 4; ++r) {
          const int prow = (w << 4) + (g << 2) + r;
          const int ck = (kt << 4) + l15 + (g << 2) + r - 15;
          if ((unsigned)ck < 64u) KDs[prow * 68 + ck] = f2bf(ka[r]);
        }
      }
    }
#pragma unroll
    for (int kt = 0; kt < 5; ++kt) {
      const int lt2 = kt - kbase;        // covered iff 0<=lt2<5
      if ((unsigned)lt2 >= 5u) {         // leftover tile (wave-uniform)
        const int nk = 3 - w + kt;
        const int pb = ((((t0 >> 6) + (nk >> 2)) & 1) << 6) + ((nk & 3) << 4);
        const int trow = pb + l15;
        const s16x8 d0 = *(const s16x8*)(Dl + trow * 128 + ((g ^ (trow & 7)) << 4));
        const s16x8 d1 = *(const s16x8*)(Dl + trow * 128 + (((4 + g) ^ (trow & 7)) << 4));
        f32x4 ka = {};
        ka = MFMA_BF16(kf0, d0, ka, 0, 0, 0);
        ka = MFMA_BF16(kf1, d1, ka, 0, 0, 0);
#pragma unroll
        for (int r = 0; r < 4; ++r) {
          const int prow = (w << 4) + (g << 2) + r;
          const int ck = (kt << 4) + l15 + (g << 2) + r - 15;
          if (kt == 0 || kt == 4) {
            if ((unsigned)ck < 64u) KDs[prow * 68 + ck] = f2bf(ka[r]);
          } else {
            KDs[prow * 68 + ck] = f2bf(ka[r]);
          }
        }
      }
    }
    __builtin_amdgcn_s_setprio(0);
    __syncthreads();

    // ---- scores: QK^T then QD-shuffle + KD(b64) + flow ----
    __builtin_amdgcn_s_setprio(1);
    f32x4 sacc[4] = {};
#pragma unroll
    for (int n = 0; n < 4; ++n) {
      const int kr = (n << 4) + l15;
      const s16x8 b0 = *(const s16x8*)(Kl + kr * 128 + ((g ^ (kr & 7)) << 4));
      const s16x8 b1 = *(const s16x8*)(Kl + kr * 128 + (((4 + g) ^ (kr & 7)) << 4));
      sacc[n] = MFMA_BF16(qf0, b0, sacc[n], 0, 0, 0);
      sacc[n] = MFMA_BF16(qf1, b1, sacc[n], 0, 0, 0);
    }
    __builtin_amdgcn_s_setprio(0);
#pragma unroll
    for (int n = 0; n < 4; ++n) {
      const int j = (n << 4) + l15;
      const uint2 kdp =
          *(const uint2*)(KDs + j * 68 + (w << 4) + (g << 2));  // 4x bf16
#pragma unroll
      for (int r = 0; r < 4; ++r) {
        float hi, lo;
        if (r == 0) {
          hi = g0 ? qa[3 - n][0] : qa[4 - n][0];
          lo = qa[3 - n][0];
        } else {
          hi = qa[4 - n][r];
          lo = qa[3 - n][r];
        }
        const float vsrc = msk[r] ? hi : lo;
        const float qd = __builtin_bit_cast(
            float, __builtin_amdgcn_ds_bpermute(
                       srcad[r], __builtin_bit_cast(int, vsrc)));
        const unsigned kdw = (r < 2) ? kdp.x : kdp.y;
        const float kd = bf2f((unsigned short)(kdw >> ((r & 1) << 4)));
        const float fv = bf2f((unsigned short)(
            n < 2 ? fv0[(n << 2) + r] : fv1[((n - 2) << 2) + r]));
        sacc[n][r] = sacc[n][r] + qd + kd + fv;  // all sqrt(c)-folded
      }
    }

    // ---- max-free softmax: P = exp2(s'), deferred per-lane row-sums ----
#pragma unroll
    for (int r = 0; r < 4; ++r) {
      const float p0 = exp2_fast(sacc[0][r]);
      const float p1 = exp2_fast(sacc[1][r]);
      const float p2 = exp2_fast(sacc[2][r]);
      const float p3 = exp2_fast(sacc[3][r]);
      sacc[0][r] = p0; sacc[1][r] = p1; sacc[2][r] = p2; sacc[3][r] = p3;
      lpart[r] += (p0 + p1) + (p2 + p3);
    }

    // ---- write P (wave-local rows; no barrier needed) ----
#pragma unroll
    for (int n = 0; n < 4; ++n) {
#pragma unroll
      for (int r = 0; r < 4; ++r) {
        const int ib = (w << 4) + (g << 2) + r;
        const int j = (n << 4) + l15;
        *(unsigned short*)(Pl + ib * 144 + (((j >> 3) ^ (ib & 7)) << 4) +
                           ((j & 7) << 1)) = f2bf(sacc[n][r]);
      }
    }

    // ---- PV ----
    __builtin_amdgcn_s_setprio(1);
#pragma unroll
    for (int k0 = 0; k0 < 2; ++k0) {
      const int prow = (w << 4) + l15;
      const s16x8 pf = *(const s16x8*)(
          Pl + prow * 144 + ((((k0 << 2) + g) ^ (prow & 7)) << 4));
#pragma unroll
      for (int n = 0; n < 4; ++n) {
        const int vrow = (n << 4) + l15;
        const s16x8 vf = *(const s16x8*)(
            Vl + vrow * 128 + ((((k0 << 2) + g) ^ (vrow & 7)) << 4));
        oacc[n] = MFMA_BF16(pf, vf, oacc[n], 0, 0, 0);
      }
    }
    __builtin_amdgcn_s_setprio(0);
    __syncthreads();
  }

  // ---- epilogue: single row-sum reduce, then out = oacc / lsum ----
  float lsum[4];
#pragma unroll
  for (int r = 0; r < 4; ++r) {
    float s = lpart[r];
#pragma unroll
    for (int dd = 1; dd < 16; dd <<= 1) s += __shfl_xor(s, dd, 64);
    lsum[r] = s;
  }
#pragma unroll
  for (int n = 0; n < 4; ++n) {
#pragma unroll
    for (int r = 0; r < 4; ++r) {
      const int l = l0 + (w << 4) + (g << 2) + r;
      const int d = (n << 4) + l15;
      Out[((long)(b * 1024 + l)) * 768 + h * 64 + d] = oacc[n][r] / lsum[r];
    }
  }
}

// ---------------------------------------------------------------------------
extern "C" void kernel_launch(void* const* d_in, const int* in_sizes, int n_in,
                              void* d_out, int out_size, void* d_ws, size_t ws_size,
                              hipStream_t stream) {
  const float* hs = (const float*)d_in[0];
  const float* Wq = (const float*)d_in[1];
  const float* bq = (const float*)d_in[2];
  const float* Wk = (const float*)d_in[3];
  const float* bk = (const float*)d_in[4];
  const float* Wv = (const float*)d_in[5];
  const float* bv = (const float*)d_in[6];
  const float* de = (const float*)d_in[7];
  const float* ce = (const float*)d_in[8];
  const float* dfe = (const float*)d_in[9];
  const float* rfe = (const float*)d_in[10];
  const int* cm = (const int*)d_in[11];
  const int* dm = (const int*)d_in[12];
  const int* rm = (const int*)d_in[13];
  float* out = (float*)d_out;
  char* ws = (char*)d_ws;

  unsigned short* hsb = (unsigned short*)(ws + 0);         // 6291456
  unsigned short* wb  = (unsigned short*)(ws + 6291456);   // 3538944
  unsigned short* db  = (unsigned short*)(ws + 9830400);   // 262144
  unsigned short* flT = (unsigned short*)(ws + 10092544);  // 8388608
  unsigned short* qp  = (unsigned short*)(ws + 18481152);  // 6291456
  unsigned short* kp  = (unsigned short*)(ws + 24772608);  // 6291456
  unsigned short* vt  = (unsigned short*)(ws + 37355520);  // 6291456

  k_prep<<<4928, 256, 0, stream>>>(hs, Wq, Wk, Wv, de, hsb, wb, db);
  k_qkvf<<<1600, 256, 0, stream>>>(hsb, wb, bq, bk, bv, qp, kp, vt,
                                   cm, dm, rm, ce, dfe, rfe, flT);
  k_attn<<<dim3(16, 12, 4), 256, 0, stream>>>(qp, kp, vt, db, flT, out);
}

// Round 19
// 111.163 us; speedup vs baseline: 1.0828x; 1.0121x over previous
//
#include <hip/hip_runtime.h>

// ---------------------------------------------------------------------------
// WelkirSelfAttention: B=4 S=1024 D=768 H=12 DH=64, relative_key_query bias +
// flow-type scalar bias. Pipeline (3 kernels):
//   k_prep : cast hidden/W{q,k,v} -> bf16; dist_emb -> bf16 * sqrt(c)
//   k_qkvf : MERGED GEMM + flow (r16 ordering, GEMM ids first) + XCD-aware
//            swizzle of GEMM ids (each XCD owns 4 complete by-rows -> A-panel
//            L2 reuse, T1). V blocks write V^T directly via LDS transpose.
//   k_attn : r15/r16 kernel verbatim (76.2us proven; r18's D-share was null).
// ---------------------------------------------------------------------------

typedef __attribute__((ext_vector_type(4))) float f32x4;
typedef __attribute__((ext_vector_type(8))) short s16x8;

#define MFMA_BF16 __builtin_amdgcn_mfma_f32_16x16x32_bf16
#define SQRT_C 0.42466086f  // sqrt(0.125 * log2(e))

__device__ __forceinline__ unsigned short f2bf(float x) {
  unsigned u = __builtin_bit_cast(unsigned, x);
  u += 0x7fffu + ((u >> 16) & 1u);
  return (unsigned short)(u >> 16);
}
__device__ __forceinline__ float bf2f(unsigned short h) {
  unsigned u = ((unsigned)h) << 16;
  return __builtin_bit_cast(float, u);
}
__device__ __forceinline__ float exp2_fast(float x) {
  float r;
  asm("v_exp_f32 %0, %1" : "=v"(r) : "v"(x));
  return r;
}
__device__ __forceinline__ void gl_lds16(const void* g, void* l) {
  __builtin_amdgcn_global_load_lds(
      (const __attribute__((address_space(1))) unsigned int*)g,
      (__attribute__((address_space(3))) unsigned int*)l, 16, 0, 0);
}

// ---------------------------------------------------------------------------
// k_prep: bf16 casts; dist rows pre-scaled by sqrt(c).
// ---------------------------------------------------------------------------
__global__ __launch_bounds__(256) void k_prep(
    const float* __restrict__ hs, const float* __restrict__ wq,
    const float* __restrict__ wk, const float* __restrict__ wv,
    const float* __restrict__ de, unsigned short* __restrict__ hsb,
    unsigned short* __restrict__ wb, unsigned short* __restrict__ db) {
  const long HSN = 3145728, WN = 1769472;
  long e = ((long)blockIdx.x * 256 + threadIdx.x) * 4;
  if (e < HSN) {
    float4 v = *(const float4*)(hs + e);
    *(ushort4*)(hsb + e) = make_ushort4(f2bf(v.x), f2bf(v.y), f2bf(v.z), f2bf(v.w));
  } else if (e < HSN + WN) {
    long ew = e - HSN;
    const float* src = (ew >= 1179648) ? wv : ((ew >= 589824) ? wk : wq);
    long off = (ew >= 1179648) ? (ew - 1179648) : ((ew >= 589824) ? (ew - 589824) : ew);
    float4 v = *(const float4*)(src + off);
    *(ushort4*)(wb + ew) = make_ushort4(f2bf(v.x), f2bf(v.y), f2bf(v.z), f2bf(v.w));
  } else {
    long ed = e - HSN - WN;  // [0, 131072)
    ushort4 ov;
    if (ed < 131008) {  // 2047*64 valid rows, rest zero pad
      float4 v = *(const float4*)(de + ed);
      ov = make_ushort4(f2bf(v.x * SQRT_C), f2bf(v.y * SQRT_C),
                        f2bf(v.z * SQRT_C), f2bf(v.w * SQRT_C));
    } else {
      ov = make_ushort4(0, 0, 0, 0);
    }
    *(ushort4*)(db + ed) = ov;
  }
}

// ---------------------------------------------------------------------------
// k_qkvf: merged GEMM + flow (GEMM ids 0..575 first; flow 576..1599).
//   GEMM ids XCD-swizzled: wid = (id%8)*72 + id/8 (bijective, 576%8==0) so
//   each XCD's round-robin share is 4 contiguous by-rows -> A-panel L2 reuse.
//   GEMM: 128x128 tile BK=32; Q/K scatter *sqrt(c); V -> LDS transpose -> V^T.
//   flow: (ce+de+re)*log2e, idx0->0, attn per-lane tiled layout.
// ---------------------------------------------------------------------------
__global__ __launch_bounds__(256) void k_qkvf(
    const unsigned short* __restrict__ A, const unsigned short* __restrict__ W,
    const float* __restrict__ bq, const float* __restrict__ bk,
    const float* __restrict__ bv, unsigned short* __restrict__ Qp,
    unsigned short* __restrict__ Kp, unsigned short* __restrict__ Vt,
    const int* __restrict__ cm, const int* __restrict__ dm,
    const int* __restrict__ rm, const float* __restrict__ ce,
    const float* __restrict__ dfe, const float* __restrict__ rfe,
    unsigned short* __restrict__ flT) {
  __shared__ __align__(16) char smq[18432];
  const int tid = threadIdx.x;
  const int id = blockIdx.x;

  if (id >= 576) {
    // ---------------- flow path (no LDS, no barriers) ----------------
    const int fid = id - 576;
    const int rt = fid & 15, lt = (fid >> 4) & 15, b = fid >> 8;
    const int l15 = tid & 15, g = (tid >> 4) & 3, w = tid >> 6;
    const int rowb = lt * 64 + w * 16 + g * 4;
    const int colb = rt * 64 + l15;
    s16x8 o0, o1;
#pragma unroll
    for (int n = 0; n < 4; ++n) {
#pragma unroll
      for (int r = 0; r < 4; ++r) {
        const long idx =
            ((long)b << 20) + ((long)(rowb + r) << 10) + colb + (n << 4);
        const int c = cm[idx], d = dm[idx], rr = rm[idx];
        const float v =
            (c ? ce[c] : 0.f) + (d ? dfe[d] : 0.f) + (rr ? rfe[rr] : 0.f);
        const short hv = (short)f2bf(1.4426950408889634f * v);
        if (n < 2) o0[n * 4 + r] = hv; else o1[(n - 2) * 4 + r] = hv;
      }
    }
    unsigned short* dst =
        flT + ((long)((((b << 4) + lt) << 4) | rt) << 12) + (tid << 4);
    *(s16x8*)(dst) = o0;
    *(s16x8*)(dst + 8) = o1;
    return;
  }

  // ---------------- GEMM path (XCD-swizzled work id) ----------------
  const int wid = (id & 7) * 72 + (id >> 3);  // bijective on [0,576)
  char* sa = smq;
  char* sb = smq + 8192;
  const int w = tid >> 6, lane = tid & 63;
  const int g = lane >> 4, l15 = lane & 15;
  const int bx = wid % 18, by = wid / 18;
  const int n0 = bx * 128, m0 = by * 128;
  const int wm = w >> 1, wn = w & 1;
  f32x4 acc[4][4] = {};
  for (int k0 = 0; k0 < 768; k0 += 32) {
#pragma unroll
    for (int it = 0; it < 2; ++it) {
      const int c = (w << 7) + (it << 6) + lane;
      const int row = c >> 2, sl = c & 3;
      const int so = ((sl ^ ((row >> 1) & 3)) << 3);
      char* dst = smq + ((w << 7) + (it << 6)) * 16;
      gl_lds16(A + (long)(m0 + row) * 768 + k0 + so, dst);
      gl_lds16(W + (long)(n0 + row) * 768 + k0 + so, dst + 8192);
    }
    __syncthreads();
    s16x8 af[4], bf[4];
#pragma unroll
    for (int mi = 0; mi < 4; ++mi) {
      const int row = wm * 64 + mi * 16 + l15;
      af[mi] = *(const s16x8*)(sa + row * 64 + ((g ^ ((row >> 1) & 3)) << 4));
    }
#pragma unroll
    for (int ni = 0; ni < 4; ++ni) {
      const int row = wn * 64 + ni * 16 + l15;
      bf[ni] = *(const s16x8*)(sb + row * 64 + ((g ^ ((row >> 1) & 3)) << 4));
    }
#pragma unroll
    for (int mi = 0; mi < 4; ++mi)
#pragma unroll
      for (int ni = 0; ni < 4; ++ni)
        acc[mi][ni] = MFMA_BF16(af[mi], bf[ni], acc[mi][ni], 0, 0, 0);
    __syncthreads();
  }
  const int t_sel = n0 / 768;
  if (t_sel < 2) {
    // ---- Q/K scatter epilogue, scaled by sqrt(c) ----
    const float* bias = (t_sel == 0) ? bq : bk;
    unsigned short* dst = (t_sel == 0) ? Qp : Kp;
#pragma unroll
    for (int ni = 0; ni < 4; ++ni) {
      const int mcol = n0 + wn * 64 + ni * 16 + l15;
      const int nw2 = mcol - t_sel * 768;
      const float bvv = bias[nw2];
      const int h = nw2 >> 6, dh = nw2 & 63;
#pragma unroll
      for (int mi = 0; mi < 4; ++mi) {
#pragma unroll
        for (int r = 0; r < 4; ++r) {
          const int token = m0 + wm * 64 + mi * 16 + (g << 2) + r;
          const int b = token >> 10, s = token & 1023;
          const long idx = ((((long)(b * 12 + h)) << 10) + s) * 64 + dh;
          dst[idx] = f2bf((acc[mi][ni][r] + bvv) * SQRT_C);
        }
      }
    }
  } else {
    // ---- V: LDS transpose -> V^T direct (two 64-dh halves) ----
    const int nv0 = n0 - 1536;               // 0,128,...,640
    const int b = m0 >> 10, s0 = m0 & 1023;  // 128 tokens all in batch b
    unsigned short* tv = (unsigned short*)smq;  // [128 rows][72 stride] u16
    const int dh = tid >> 2, seg = tid & 3;
#pragma unroll
    for (int hh = 0; hh < 2; ++hh) {
      if (wn == hh) {
#pragma unroll
        for (int ni = 0; ni < 4; ++ni) {
          const int colh = ni * 16 + l15;               // 0..63 within head
          const float bvv = bv[nv0 + hh * 64 + colh];
#pragma unroll
          for (int mi = 0; mi < 4; ++mi)
#pragma unroll
            for (int r = 0; r < 4; ++r)
              tv[(wm * 64 + mi * 16 + (g << 2) + r) * 72 + colh] =
                  f2bf(acc[mi][ni][r] + bvv);
        }
      }
      __syncthreads();
      const int hB = (nv0 >> 6) + hh;  // global head index
      unsigned short* vrow =
          Vt + ((long)((b * 12 + hB) * 64 + dh) << 10) + s0;
#pragma unroll
      for (int q = 0; q < 4; ++q) {
        s16x8 vv;
#pragma unroll
        for (int i = 0; i < 8; ++i)
          vv[i] = (short)tv[(seg * 32 + q * 8 + i) * 72 + dh];
        *(s16x8*)(vrow + seg * 32 + q * 8) = vv;
      }
      __syncthreads();
    }
  }
}

// ---------------------------------------------------------------------------
// k_attn: r15/r16 verbatim. Per (b,h,l-tile of 64), 16 r-tiles.
// Static LDS 50688B (3 blocks/CU, tail-free: 768 = 3*256):
//   Kl/Vl/Dl swizzled gl_lds-staged; KDs stride-68 sheared; Pl stride-144.
// QD in registers + bpermute shear; KD b64 reads; max-free exp2 softmax.
// sqrt(c) pre-folded into Q, K, D sources -> s' = QK' + QD' + KD' + flow'.
// s_setprio(1) around MFMA clusters (3 independent blocks/CU = m191 regime).
// ---------------------------------------------------------------------------
__global__ __launch_bounds__(256, 3) void k_attn(
    const unsigned short* __restrict__ Qp, const unsigned short* __restrict__ Kp,
    const unsigned short* __restrict__ Vtp, const unsigned short* __restrict__ Db,
    const unsigned short* __restrict__ FlT, float* __restrict__ Out) {
  __shared__ __align__(16) char sm[50688];
  char* Kl = sm;
  char* Vl = sm + 8192;
  char* Dl = sm + 16384;
  unsigned short* KDs = (unsigned short*)(sm + 32768);  // [64] rows x stride 68
  char* Pl = sm + 41472;                                // [64] rows x 144B

  const int tid = threadIdx.x, w = tid >> 6, lane = tid & 63;
  const int g = lane >> 4, l15 = lane & 15;
  const int l0 = blockIdx.x << 6, h = blockIdx.y, b = blockIdx.z;
  const int bh = b * 12 + h;
  const unsigned short* Qb = Qp + ((long)bh << 16);
  const unsigned short* Kb = Kp + ((long)bh << 16);
  const unsigned short* Vb = Vtp + ((long)bh << 16);
  const unsigned short* fTb =
      FlT + ((long)(((b << 4) + blockIdx.x) << 4) << 12) + (tid << 4);

  const int qrow = l0 + (w << 4) + l15;
  const s16x8 qf0 = *(const s16x8*)(Qb + (long)qrow * 64 + g * 8);
  const s16x8 qf1 = *(const s16x8*)(Qb + (long)qrow * 64 + 32 + g * 8);

  // ---- iteration-invariant QD-shuffle constants ----
  int srcad[4];
  bool msk[4];
#pragma unroll
  for (int r = 0; r < 4; ++r) {
    const int bl = ((g << 2) + r - 1) & 15;
    srcad[r] = (((lane & 48) + ((bl - l15) & 15)) << 2);
    msk[r] = (l15 <= bl);
  }
  const bool g0 = (g == 0);

  f32x4 oacc[4] = {};
  float lpart[4] = {0.f, 0.f, 0.f, 0.f};

  for (int rt = 0; rt < 16; ++rt) {
    const int r0 = rt << 6;
    const int t0 = l0 - r0 + 960;  // window [t0, t0+127], t0 % 64 == 0

    // ---- flow tile: 2 x 16B vector loads (pre-tiled, pre-scaled) ----
    const s16x8 fv0 = *(const s16x8*)(fTb + ((long)rt << 12));
    const s16x8 fv1 = *(const s16x8*)(fTb + ((long)rt << 12) + 8);

    // ---- stage K / V^T (+ D half), pre-swizzled sources ----
#pragma unroll
    for (int it = 0; it < 2; ++it) {
      const int c = (w << 7) + (it << 6) + lane;
      const int row = c >> 3, sl = c & 7;
      const int so = ((sl ^ (row & 7)) << 3);
      char* dst = sm + ((w << 7) + (it << 6)) * 16;
      gl_lds16(Kb + (long)(r0 + row) * 64 + so, dst);            // K
      gl_lds16(Vb + (long)row * 1024 + r0 + so, dst + 8192);     // V^T
    }
    {
      const int nh = (rt == 0) ? 2 : 1;
      for (int hh = 0; hh < nh; ++hh) {
        const int ts = t0 + (hh << 6);
        char* dhalf = Dl + (((ts >> 6) & 1) << 13);
#pragma unroll
        for (int it = 0; it < 2; ++it) {
          const int c = (w << 7) + (it << 6) + lane;
          const int row = c >> 3, sl = c & 7;
          gl_lds16(Db + (long)(ts + row) * 64 + ((sl ^ (row & 7)) << 3),
                   dhalf + ((w << 7) + (it << 6)) * 16);
        }
      }
    }
    __syncthreads();

    // ---- QD panel: 5 tiles (n = w..w+4) kept in registers ----
    __builtin_amdgcn_s_setprio(1);
    f32x4 qa[5];
#pragma unroll
    for (int lt = 0; lt < 5; ++lt) {
      const int nq = w + lt;
      const int pb = ((((t0 >> 6) + (nq >> 2)) & 1) << 6) + ((nq & 3) << 4);
      const int trow = pb + l15;
      const s16x8 d0 = *(const s16x8*)(Dl + trow * 128 + ((g ^ (trow & 7)) << 4));
      const s16x8 d1 = *(const s16x8*)(Dl + trow * 128 + (((4 + g) ^ (trow & 7)) << 4));
      f32x4 a = {};
      a = MFMA_BF16(qf0, d0, a, 0, 0, 0);
      a = MFMA_BF16(qf1, d1, a, 0, 0, 0);
      qa[lt] = a;
    }

    // ---- KD panel: 5 tiles (n = 3-w..7-w) -> sheared LDS stores ----
    {
      const int krow = (w << 4) + l15;
      const s16x8 kf0 = *(const s16x8*)(Kl + krow * 128 + ((g ^ (krow & 7)) << 4));
      const s16x8 kf1 = *(const s16x8*)(Kl + krow * 128 + (((4 + g) ^ (krow & 7)) << 4));
#pragma unroll
      for (int kt = 0; kt < 5; ++kt) {
        const int nk = 3 - w + kt;
        const int pb = ((((t0 >> 6) + (nk >> 2)) & 1) << 6) + ((nk & 3) << 4);
        const int trow = pb + l15;
        const s16x8 d0 = *(const s16x8*)(Dl + trow * 128 + ((g ^ (trow & 7)) << 4));
        const s16x8 d1 = *(const s16x8*)(Dl + trow * 128 + (((4 + g) ^ (trow & 7)) << 4));
        f32x4 ka = {};
        ka = MFMA_BF16(kf0, d0, ka, 0, 0, 0);
        ka = MFMA_BF16(kf1, d1, ka, 0, 0, 0);
#pragma unroll
        for (int r = 0; r < 4; ++r) {
          const int prow = (w << 4) + (g << 2) + r;
          const int ck = (kt << 4) + l15 + (g << 2) + r - 15;  // w cancels
          if (kt == 0 || kt == 4) {
            if ((unsigned)ck < 64u) KDs[prow * 68 + ck] = f2bf(ka[r]);
          } else {
            KDs[prow * 68 + ck] = f2bf(ka[r]);
          }
        }
      }
    }
    __builtin_amdgcn_s_setprio(0);
    __syncthreads();

    // ---- scores: QK^T then QD-shuffle + KD(b64) + flow ----
    __builtin_amdgcn_s_setprio(1);
    f32x4 sacc[4] = {};
#pragma unroll
    for (int n = 0; n < 4; ++n) {
      const int kr = (n << 4) + l15;
      const s16x8 b0 = *(const s16x8*)(Kl + kr * 128 + ((g ^ (kr & 7)) << 4));
      const s16x8 b1 = *(const s16x8*)(Kl + kr * 128 + (((4 + g) ^ (kr & 7)) << 4));
      sacc[n] = MFMA_BF16(qf0, b0, sacc[n], 0, 0, 0);
      sacc[n] = MFMA_BF16(qf1, b1, sacc[n], 0, 0, 0);
    }
    __builtin_amdgcn_s_setprio(0);
#pragma unroll
    for (int n = 0; n < 4; ++n) {
      const int j = (n << 4) + l15;
      const uint2 kdp =
          *(const uint2*)(KDs + j * 68 + (w << 4) + (g << 2));  // 4x bf16
#pragma unroll
      for (int r = 0; r < 4; ++r) {
        float hi, lo;
        if (r == 0) {
          hi = g0 ? qa[3 - n][0] : qa[4 - n][0];
          lo = qa[3 - n][0];
        } else {
          hi = qa[4 - n][r];
          lo = qa[3 - n][r];
        }
        const float vsrc = msk[r] ? hi : lo;
        const float qd = __builtin_bit_cast(
            float, __builtin_amdgcn_ds_bpermute(
                       srcad[r], __builtin_bit_cast(int, vsrc)));
        const unsigned kdw = (r < 2) ? kdp.x : kdp.y;
        const float kd = bf2f((unsigned short)(kdw >> ((r & 1) << 4)));
        const float fv = bf2f((unsigned short)(
            n < 2 ? fv0[(n << 2) + r] : fv1[((n - 2) << 2) + r]));
        sacc[n][r] = sacc[n][r] + qd + kd + fv;  // all sqrt(c)-folded
      }
    }

    // ---- max-free softmax: P = exp2(s'), deferred per-lane row-sums ----
#pragma unroll
    for (int r = 0; r < 4; ++r) {
      const float p0 = exp2_fast(sacc[0][r]);
      const float p1 = exp2_fast(sacc[1][r]);
      const float p2 = exp2_fast(sacc[2][r]);
      const float p3 = exp2_fast(sacc[3][r]);
      sacc[0][r] = p0; sacc[1][r] = p1; sacc[2][r] = p2; sacc[3][r] = p3;
      lpart[r] += (p0 + p1) + (p2 + p3);
    }

    // ---- write P (wave-local rows; no barrier needed) ----
#pragma unroll
    for (int n = 0; n < 4; ++n) {
#pragma unroll
      for (int r = 0; r < 4; ++r) {
        const int ib = (w << 4) + (g << 2) + r;
        const int j = (n << 4) + l15;
        *(unsigned short*)(Pl + ib * 144 + (((j >> 3) ^ (ib & 7)) << 4) +
                           ((j & 7) << 1)) = f2bf(sacc[n][r]);
      }
    }

    // ---- PV ----
    __builtin_amdgcn_s_setprio(1);
#pragma unroll
    for (int k0 = 0; k0 < 2; ++k0) {
      const int prow = (w << 4) + l15;
      const s16x8 pf = *(const s16x8*)(
          Pl + prow * 144 + ((((k0 << 2) + g) ^ (prow & 7)) << 4));
#pragma unroll
      for (int n = 0; n < 4; ++n) {
        const int vrow = (n << 4) + l15;
        const s16x8 vf = *(const s16x8*)(
            Vl + vrow * 128 + ((((k0 << 2) + g) ^ (vrow & 7)) << 4));
        oacc[n] = MFMA_BF16(pf, vf, oacc[n], 0, 0, 0);
      }
    }
    __builtin_amdgcn_s_setprio(0);
    __syncthreads();
  }

  // ---- epilogue: single row-sum reduce, then out = oacc / lsum ----
  float lsum[4];
#pragma unroll
  for (int r = 0; r < 4; ++r) {
    float s = lpart[r];
#pragma unroll
    for (int dd = 1; dd < 16; dd <<= 1) s += __shfl_xor(s, dd, 64);
    lsum[r] = s;
  }
#pragma unroll
  for (int n = 0; n < 4; ++n) {
#pragma unroll
    for (int r = 0; r < 4; ++r) {
      const int l = l0 + (w << 4) + (g << 2) + r;
      const int d = (n << 4) + l15;
      Out[((long)(b * 1024 + l)) * 768 + h * 64 + d] = oacc[n][r] / lsum[r];
    }
  }
}

// ---------------------------------------------------------------------------
extern "C" void kernel_launch(void* const* d_in, const int* in_sizes, int n_in,
                              void* d_out, int out_size, void* d_ws, size_t ws_size,
                              hipStream_t stream) {
  const float* hs = (const float*)d_in[0];
  const float* Wq = (const float*)d_in[1];
  const float* bq = (const float*)d_in[2];
  const float* Wk = (const float*)d_in[3];
  const float* bk = (const float*)d_in[4];
  const float* Wv = (const float*)d_in[5];
  const float* bv = (const float*)d_in[6];
  const float* de = (const float*)d_in[7];
  const float* ce = (const float*)d_in[8];
  const float* dfe = (const float*)d_in[9];
  const float* rfe = (const float*)d_in[10];
  const int* cm = (const int*)d_in[11];
  const int* dm = (const int*)d_in[12];
  const int* rm = (const int*)d_in[13];
  float* out = (float*)d_out;
  char* ws = (char*)d_ws;

  unsigned short* hsb = (unsigned short*)(ws + 0);         // 6291456
  unsigned short* wb  = (unsigned short*)(ws + 6291456);   // 3538944
  unsigned short* db  = (unsigned short*)(ws + 9830400);   // 262144
  unsigned short* flT = (unsigned short*)(ws + 10092544);  // 8388608
  unsigned short* qp  = (unsigned short*)(ws + 18481152);  // 6291456
  unsigned short* kp  = (unsigned short*)(ws + 24772608);  // 6291456
  unsigned short* vt  = (unsigned short*)(ws + 37355520);  // 6291456

  k_prep<<<4928, 256, 0, stream>>>(hs, Wq, Wk, Wv, de, hsb, wb, db);
  k_qkvf<<<1600, 256, 0, stream>>>(hsb, wb, bq, bk, bv, qp, kp, vt,
                                   cm, dm, rm, ce, dfe, rfe, flT);
  k_attn<<<dim3(16, 12, 4), 256, 0, stream>>>(qp, kp, vt, db, flT, out);
}